// Round 8
// baseline (4612.188 us; speedup 1.0000x reference)
//
#include <hip/hip_runtime.h>
#include <cstdint>
#include <cstddef>

// ViT-B/16 + token pruning. Round 8: fp16 everywhere; 256x256 8-wave
// phase-pipelined GEMM (ring-4 LDS, counted vmcnt, 1 barrier/K-tile) for the
// large-grid GEMMs (qkv, fc1); 128^2 counted-vmcnt kernel for the rest.

#define NTOK 197
#define NB 64
#define NHEAD 12
#define SL 99

typedef __attribute__((ext_vector_type(8))) _Float16 half8;
typedef __attribute__((ext_vector_type(4))) float f32x4;
typedef __attribute__((ext_vector_type(4))) unsigned short us4;

#define DEV static __device__ __forceinline__

DEV unsigned short f2h(float f) {
    union { _Float16 h; unsigned short u; } v;
    v.h = (_Float16)f;            // v_cvt_f16_f32, round-to-nearest-even
    return v.u;
}

DEV void gload16(const void* g, void* l) {
    __builtin_amdgcn_global_load_lds((const __attribute__((address_space(1))) unsigned int*)g,
                                     (__attribute__((address_space(3))) unsigned int*)l, 16, 0, 0);
}

// ---------------------------------------------------------------- weight conversion (fp32 -> fp16)
__global__ __launch_bounds__(256) void cvt_layer_k(const float* __restrict__ qw,
                                                   const float* __restrict__ pw,
                                                   const float* __restrict__ f1,
                                                   const float* __restrict__ f2,
                                                   unsigned short* __restrict__ dh)
{
    size_t t = (size_t)blockIdx.x * 256 + threadIdx.x;
    size_t e = t * 4;
    const float* src; size_t loc;
    if (e < 1769472)      { src = qw; loc = e; }
    else if (e < 2359296) { src = pw; loc = e - 1769472; }
    else if (e < 4718592) { src = f1; loc = e - 2359296; }
    else                  { src = f2; loc = e - 4718592; }
    float4 v = *(const float4*)(src + loc);
    us4 hi; hi.x = f2h(v.x); hi.y = f2h(v.y); hi.z = f2h(v.z); hi.w = f2h(v.w);
    *(us4*)(dh + e) = hi;
}

__global__ __launch_bounds__(256) void cvt_simple_k(const float* __restrict__ src,
                                                    unsigned short* __restrict__ dh, int n4)
{
    int t = blockIdx.x * 256 + threadIdx.x;
    if (t >= n4) return;
    size_t e = (size_t)t * 4;
    float4 v = *(const float4*)(src + e);
    us4 hi; hi.x = f2h(v.x); hi.y = f2h(v.y); hi.z = f2h(v.z); hi.w = f2h(v.w);
    *(us4*)(dh + e) = hi;
}

// ---------------------------------------------------------------- patch extract (fp32 -> fp16)
__global__ __launch_bounds__(256) void patch_extract2_k(const float* __restrict__ img,
                                                        unsigned short* __restrict__ ph)
{
    int pi = blockIdx.x, b = blockIdx.y;
    int gy = pi / 14, gx = pi % 14;
    size_t obase = ((size_t)b * 196 + pi) * 768;
    for (int f = threadIdx.x; f < 768; f += 256) {
        int c = f >> 8, py = (f >> 4) & 15, px = f & 15;
        float v = img[(((size_t)b * 3 + c) * 224 + gy * 16 + py) * 224 + gx * 16 + px];
        ph[obase + f] = f2h(v);
    }
}

__global__ __launch_bounds__(256) void assemble_k(const float* __restrict__ emb,
                                                  const float* __restrict__ cls,
                                                  const float* __restrict__ pos,
                                                  float* __restrict__ x)
{
    int s = blockIdx.x, b = blockIdx.y;
    size_t xo = ((size_t)b * NTOK + s) * 768;
    for (int d = threadIdx.x; d < 768; d += 256) {
        float v = (s == 0) ? cls[d] : emb[((size_t)b * 196 + (s - 1)) * 768 + d];
        x[xo + d] = v + pos[(size_t)s * 768 + d];
    }
}

// ---------------------------------------------------------------- layernorm fp32 -> fp16
__global__ __launch_bounds__(256) void ln2_k(const float* __restrict__ in,
                                             unsigned short* __restrict__ outh,
                                             const float* __restrict__ g,
                                             const float* __restrict__ bt, size_t ldin)
{
    const float* xr = in + (size_t)blockIdx.x * ldin;
    size_t ob = (size_t)blockIdx.x * 768;
    int t = threadIdx.x;
    float v0 = xr[t], v1 = xr[t + 256], v2 = xr[t + 512];
    float s = v0 + v1 + v2;
#pragma unroll
    for (int o = 32; o; o >>= 1) s += __shfl_xor(s, o);
    __shared__ float r1[4], r2[4];
    int wv = t >> 6, ln = t & 63;
    if (ln == 0) r1[wv] = s;
    __syncthreads();
    float mean = (r1[0] + r1[1] + r1[2] + r1[3]) * (1.f / 768.f);
    float d0 = v0 - mean, d1 = v1 - mean, d2 = v2 - mean;
    float ss = d0 * d0 + d1 * d1 + d2 * d2;
#pragma unroll
    for (int o = 32; o; o >>= 1) ss += __shfl_xor(ss, o);
    if (ln == 0) r2[wv] = ss;
    __syncthreads();
    float inv = rsqrtf((r2[0] + r2[1] + r2[2] + r2[3]) * (1.f / 768.f) + 1e-6f);
    outh[ob + t]       = f2h(d0 * inv * g[t]       + bt[t]);
    outh[ob + t + 256] = f2h(d1 * inv * g[t + 256] + bt[t + 256]);
    outh[ob + t + 512] = f2h(d2 * inv * g[t + 512] + bt[t + 512]);
}

// ---------------------------------------------------------------- 256x256 8-wave phase-pipelined fp16 GEMM
// C = op(A@W^T + bias). A[M,K], W[N,K] fp16. 8 waves (2Mx4N), wave tile
// 128x64, BK=32, ring of 4 LDS slots (128 KiB). Counted vmcnt(8), one
// s_barrier per K-tile, 4 MFMA phases interleaved with next-tile staging.
// sigma(r)=(r>>1)&3 chunk swizzle on both sides. EPI: 0 none, 1 GELU.
// OS: 0 fp32 out, 1 fp16 out.
template<int EPI, int OS>
__global__ __launch_bounds__(512, 2) void gemm256_k(const unsigned short* __restrict__ Ah,
                                                    const unsigned short* __restrict__ Wh,
                                                    const float* __restrict__ bias,
                                                    unsigned short* __restrict__ Chi,
                                                    float* __restrict__ Cf,
                                                    int M, int N, int K, int nR, int nC)
{
    extern __shared__ unsigned short lds[];   // 4 slots x (A 8192 + B 8192) shorts = 128 KiB

    const int xcd = blockIdx.x & 7, u = blockIdx.x >> 3;
    const int ct = u % nC, rl = u / nC;
    const int rt = xcd + 8 * rl;
    if (rt >= nR) return;
    const int row0 = rt << 8, col0 = ct << 8;

    const int tid = threadIdx.x;
    const int w = tid >> 6, lane = tid & 63;
    const int wr = w >> 2, wc = w & 3;            // 2 x 4 wave grid
    const int fr = lane & 15, fq = lane >> 4;
    const int aoff = (fq ^ ((fr >> 1) & 3)) << 3; // swizzled read chunk (shorts)

    const int nk = K >> 5;

    // staging: wave w covers LDS rows w*32 + (lane>>2) and +16
    const int srow = lane >> 2;
    const int r0 = (w << 5) + srow;
    const int r1 = r0 + 16;
    const int cs = (((lane & 3) ^ ((srow >> 1) & 3)) << 3);   // sigma(r0)=sigma(r1)
    const int gA0 = (row0 + r0 < M) ? row0 + r0 : M - 1;
    const int gA1 = (row0 + r1 < M) ? row0 + r1 : M - 1;
    const int gB0 = (col0 + r0 < N) ? col0 + r0 : N - 1;
    const int gB1 = (col0 + r1 < N) ? col0 + r1 : N - 1;

    auto stageA = [&](int kt) {
        const int k0 = kt << 5;
        unsigned short* dst = lds + (kt & 3) * 16384 + ((w << 1) << 9);
        gload16(Ah + (size_t)gA0 * K + k0 + cs, dst);
        gload16(Ah + (size_t)gA1 * K + k0 + cs, dst + 512);
    };
    auto stageB = [&](int kt) {
        const int k0 = kt << 5;
        unsigned short* dst = lds + (kt & 3) * 16384 + 8192 + ((w << 1) << 9);
        gload16(Wh + (size_t)gB0 * K + k0 + cs, dst);
        gload16(Wh + (size_t)gB1 * K + k0 + cs, dst + 512);
    };

    f32x4 acc[8][4];
#pragma unroll
    for (int m = 0; m < 8; m++)
#pragma unroll
        for (int n = 0; n < 4; n++) acc[m][n] = (f32x4)0.f;

    stageA(0); stageB(0);
    if (nk > 1) { stageA(1); stageB(1); }
    if (nk > 2) { stageA(2); stageB(2); }

#define MF4(m, av) { \
    acc[m][0] = __builtin_amdgcn_mfma_f32_16x16x32_f16(av, b0, acc[m][0], 0, 0, 0); \
    acc[m][1] = __builtin_amdgcn_mfma_f32_16x16x32_f16(av, b1, acc[m][1], 0, 0, 0); \
    acc[m][2] = __builtin_amdgcn_mfma_f32_16x16x32_f16(av, b2, acc[m][2], 0, 0, 0); \
    acc[m][3] = __builtin_amdgcn_mfma_f32_16x16x32_f16(av, b3, acc[m][3], 0, 0, 0); }

    for (int kt = 0; kt < nk; ++kt) {
        if (kt + 2 < nk)      asm volatile("s_waitcnt vmcnt(8)" ::: "memory");
        else if (kt + 1 < nk) asm volatile("s_waitcnt vmcnt(4)" ::: "memory");
        else                  asm volatile("s_waitcnt vmcnt(0)" ::: "memory");
        __builtin_amdgcn_s_barrier();
        const unsigned short* sA = lds + (kt & 3) * 16384;
        const unsigned short* sB = sA + 8192;

        half8 b0 = *(const half8*)(sB + ((wc << 6) +  0 + fr) * 32 + aoff);
        half8 b1 = *(const half8*)(sB + ((wc << 6) + 16 + fr) * 32 + aoff);
        half8 b2 = *(const half8*)(sB + ((wc << 6) + 32 + fr) * 32 + aoff);
        half8 b3 = *(const half8*)(sB + ((wc << 6) + 48 + fr) * 32 + aoff);
        half8 a0 = *(const half8*)(sA + ((wr << 7) +   0 + fr) * 32 + aoff);
        half8 a1 = *(const half8*)(sA + ((wr << 7) +  16 + fr) * 32 + aoff);
        __builtin_amdgcn_sched_barrier(0);
        if (kt + 3 < nk) stageA(kt + 3);
        __builtin_amdgcn_sched_barrier(0);
        half8 a2 = *(const half8*)(sA + ((wr << 7) +  32 + fr) * 32 + aoff);
        half8 a3 = *(const half8*)(sA + ((wr << 7) +  48 + fr) * 32 + aoff);
        __builtin_amdgcn_sched_barrier(0);
        __builtin_amdgcn_s_setprio(1);
        MF4(0, a0); MF4(1, a1);
        __builtin_amdgcn_s_setprio(0);
        __builtin_amdgcn_sched_barrier(0);
        if (kt + 3 < nk) stageB(kt + 3);
        __builtin_amdgcn_sched_barrier(0);
        half8 a4 = *(const half8*)(sA + ((wr << 7) +  64 + fr) * 32 + aoff);
        half8 a5 = *(const half8*)(sA + ((wr << 7) +  80 + fr) * 32 + aoff);
        __builtin_amdgcn_sched_barrier(0);
        __builtin_amdgcn_s_setprio(1);
        MF4(2, a2); MF4(3, a3);
        __builtin_amdgcn_s_setprio(0);
        __builtin_amdgcn_sched_barrier(0);
        half8 a6 = *(const half8*)(sA + ((wr << 7) +  96 + fr) * 32 + aoff);
        half8 a7 = *(const half8*)(sA + ((wr << 7) + 112 + fr) * 32 + aoff);
        __builtin_amdgcn_sched_barrier(0);
        __builtin_amdgcn_s_setprio(1);
        MF4(4, a4); MF4(5, a5);
        __builtin_amdgcn_s_setprio(0);
        __builtin_amdgcn_sched_barrier(0);
        __builtin_amdgcn_s_setprio(1);
        MF4(6, a6); MF4(7, a7);
        __builtin_amdgcn_s_setprio(0);
        // reads of this slot retired before next barrier -> slot (kt+3)&3
        // staged next iteration can't race any in-flight ds_read.
        asm volatile("s_waitcnt lgkmcnt(0)" ::: "memory");
        __builtin_amdgcn_sched_barrier(0);
    }
#undef MF4

#pragma unroll
    for (int m = 0; m < 8; m++) {
        const int rowb = row0 + (wr << 7) + (m << 4) + (fq << 2);
#pragma unroll
        for (int n = 0; n < 4; n++) {
            const int col = col0 + (wc << 6) + (n << 4) + fr;
            if (col >= N) continue;
#pragma unroll
            for (int r = 0; r < 4; r++) {
                const int row = rowb + r;
                if (row >= M) continue;
                float v = acc[m][n][r] + bias[col];
                size_t o = (size_t)row * N + col;
                if (EPI == 1) v = 0.5f * v * (1.f + erff(v * 0.70710678118654752f));
                if (OS == 0) Cf[o] = v;
                else Chi[o] = f2h(v);
            }
        }
    }
}

// ---------------------------------------------------------------- 128x128 fp16 MFMA GEMM, counted-vmcnt
// EPI: 0 none, 1 GELU, 2 +res. OS: 0 fp32 out, 1 fp16 out.
// MAP: 0 linear, 1 xcd rows-fastest, 2 xcd cols-fastest.
template<int EPI, int OS, int MAP>
__global__ __launch_bounds__(256) void mgemm_k(const unsigned short* __restrict__ Ah,
                                               const unsigned short* __restrict__ Wh,
                                               const float* __restrict__ bias,
                                               const float* __restrict__ res,
                                               unsigned short* __restrict__ Chi,
                                               float* __restrict__ Cf,
                                               int M, int N, int K, int nR, int nC, int nRmax)
{
    __shared__ unsigned short lds[2 * 8192];

    int rt, ct;
    {
        int bid = blockIdx.x;
        if (MAP == 0) { rt = bid % nR; ct = bid / nR; }
        else {
            int x = bid & 7, u = bid >> 3, rl, c;
            if (MAP == 2) { c = u % nC; rl = u / nC; }
            else          { rl = u % nRmax; c = u / nRmax; }
            rt = x + 8 * rl; ct = c;
            if (rt >= nR) return;
        }
    }
    const int row0 = rt << 7, col0 = ct << 7;
    const int tid = threadIdx.x;
    const int w = tid >> 6, lane = tid & 63;
    const int wr = w >> 1, wc = w & 1;
    const int srow = lane >> 2;
    const int schunk = ((lane & 3) ^ ((srow >> 1) & 3)) << 3;
    const int fr = lane & 15, fq = lane >> 4;
    const int rchunk = (fq ^ ((fr >> 1) & 3)) << 3;

    f32x4 acc[4][4];
#pragma unroll
    for (int m = 0; m < 4; m++)
#pragma unroll
        for (int n = 0; n < 4; n++) acc[m][n] = (f32x4)0.f;

    const int nk = K >> 5;

    auto stage = [&](int t, int bsel) {
        const int k0 = t << 5;
        unsigned short* Ad = lds + bsel * 8192;
        unsigned short* Bd = Ad + 4096;
#pragma unroll
        for (int i = 0; i < 2; i++) {
            int r = i * 64 + w * 16 + srow;
            int ga = row0 + r; if (ga > M - 1) ga = M - 1;
            int gb = col0 + r; if (gb > N - 1) gb = N - 1;
            gload16(Ah + (size_t)ga * K + k0 + schunk, Ad + i * 2048 + w * 512);
            gload16(Wh + (size_t)gb * K + k0 + schunk, Bd + i * 2048 + w * 512);
        }
    };

    stage(0, 0);
    stage(1, 1);
    for (int t = 0; t < nk; ++t) {
        const int bsel = t & 1;
        if (t + 1 < nk) asm volatile("s_waitcnt vmcnt(4)" ::: "memory");
        else            asm volatile("s_waitcnt vmcnt(0)" ::: "memory");
        __builtin_amdgcn_s_barrier();
        __builtin_amdgcn_sched_barrier(0);
        const unsigned short* Ab = lds + bsel * 8192;
        const unsigned short* Bb = Ab + 4096;
        half8 a[4], bb[4];
#pragma unroll
        for (int m = 0; m < 4; m++)
            a[m] = *(const half8*)(Ab + (wr * 64 + m * 16 + fr) * 32 + rchunk);
#pragma unroll
        for (int n = 0; n < 4; n++)
            bb[n] = *(const half8*)(Bb + (wc * 64 + n * 16 + fr) * 32 + rchunk);
        __builtin_amdgcn_sched_barrier(0);
        asm volatile("s_waitcnt lgkmcnt(0)" ::: "memory");
        __builtin_amdgcn_sched_barrier(0);
        __builtin_amdgcn_s_barrier();
        if (t + 2 < nk) stage(t + 2, bsel);
#pragma unroll
        for (int m = 0; m < 4; m++)
#pragma unroll
            for (int n = 0; n < 4; n++)
                acc[m][n] = __builtin_amdgcn_mfma_f32_16x16x32_f16(a[m], bb[n], acc[m][n], 0, 0, 0);
    }

#pragma unroll
    for (int m = 0; m < 4; m++) {
#pragma unroll
        for (int n = 0; n < 4; n++) {
            int col = col0 + wc * 64 + n * 16 + fr;
#pragma unroll
            for (int r = 0; r < 4; r++) {
                int row = row0 + wr * 64 + m * 16 + fq * 4 + r;
                if (row < M && col < N) {
                    float v = acc[m][n][r] + bias[col];
                    size_t o = (size_t)row * N + col;
                    if (EPI == 2) v += res[o];
                    if (EPI == 1) v = 0.5f * v * (1.f + erff(v * 0.70710678118654752f));
                    if (OS == 0) Cf[o] = v;
                    else Chi[o] = f2h(v);
                }
            }
        }
    }
}

// ---------------------------------------------------------------- fused MFMA attention (fp16)
template<int S, int KT, int PVKT, int PSTR>
__global__ __launch_bounds__(256) void attn2_k(const unsigned short* __restrict__ qh,
                                               unsigned short* __restrict__ oh,
                                               const int* __restrict__ cntp)
{
    constexpr int PVK = PVKT * 32;
    constexpr int QT = (S + 15) / 16;
    extern __shared__ unsigned short sh[];
    unsigned short* VT = sh;                 // [64][PSTR]  V^T
    unsigned short* PL = sh + 64 * PSTR;     // 4 waves x [16][PSTR]

    const int h = blockIdx.x, b = blockIdx.y;
    const int tid = threadIdx.x, w = tid >> 6, lane = tid & 63;
    const int nk = cntp ? cntp[b] : S;
    const size_t qbase = (size_t)b * S * 2304 + (size_t)h * 64;
    const int fr = lane & 15, fq = lane >> 4;

    for (int j0 = 0; j0 < S; j0 += 32) {
        int j = j0 + (tid >> 3);
        int d8 = (tid & 7) * 8;
        if (j < S) {
            size_t src = qbase + (size_t)j * 2304 + 1536 + d8;
            us4 v0 = *(const us4*)(qh + src);
            us4 v1 = *(const us4*)(qh + src + 4);
            VT[(d8 + 0) * PSTR + j] = v0.x; VT[(d8 + 1) * PSTR + j] = v0.y;
            VT[(d8 + 2) * PSTR + j] = v0.z; VT[(d8 + 3) * PSTR + j] = v0.w;
            VT[(d8 + 4) * PSTR + j] = v1.x; VT[(d8 + 5) * PSTR + j] = v1.y;
            VT[(d8 + 6) * PSTR + j] = v1.z; VT[(d8 + 7) * PSTR + j] = v1.w;
        }
    }
    for (int idx = tid; idx < 64 * (PVK - S); idx += 256) {
        int d = idx / (PVK - S), j = S + idx % (PVK - S);
        VT[d * PSTR + j] = 0;
    }
    {
        unsigned short* Pw = PL + w * 16 * PSTR;
        for (int idx = lane; idx < 16 * (PVK - 16 * KT); idx += 64) {
            int rr = idx / (PVK - 16 * KT), cc = 16 * KT + idx % (PVK - 16 * KT);
            Pw[rr * PSTR + cc] = 0;
        }
    }
    __syncthreads();

    for (int qt = w; qt < QT; qt += 4) {
        int qr = qt * 16 + fr; int qrc = qr < S ? qr : S - 1;
        const size_t qrow = qbase + (size_t)qrc * 2304;
        half8 qf0[2];
#pragma unroll
        for (int ks = 0; ks < 2; ks++)
            qf0[ks] = *(const half8*)(qh + qrow + ks * 32 + fq * 8);
        f32x4 sc[KT];
#pragma unroll
        for (int kt = 0; kt < KT; kt++) {
            int ky = kt * 16 + fr; int kyc = ky < S ? ky : S - 1;
            const size_t krow = qbase + (size_t)kyc * 2304 + 768;
            f32x4 acc = (f32x4)0.f;
#pragma unroll
            for (int ks = 0; ks < 2; ks++) {
                half8 kh = *(const half8*)(qh + krow + ks * 32 + fq * 8);
                acc = __builtin_amdgcn_mfma_f32_16x16x32_f16(qf0[ks], kh, acc, 0, 0, 0);
            }
            sc[kt] = acc;
        }
        float mx[4] = {-3e38f, -3e38f, -3e38f, -3e38f};
#pragma unroll
        for (int kt = 0; kt < KT; kt++) {
            bool valid = (kt * 16 + fr) < nk;
#pragma unroll
            for (int r = 0; r < 4; r++) {
                float s = sc[kt][r] * 0.125f;
                sc[kt][r] = s;
                if (valid) mx[r] = fmaxf(mx[r], s);
            }
        }
#pragma unroll
        for (int off = 1; off < 16; off <<= 1)
#pragma unroll
            for (int r = 0; r < 4; r++) mx[r] = fmaxf(mx[r], __shfl_xor(mx[r], off));
        float sum[4] = {0.f, 0.f, 0.f, 0.f};
#pragma unroll
        for (int kt = 0; kt < KT; kt++) {
            bool valid = (kt * 16 + fr) < nk;
#pragma unroll
            for (int r = 0; r < 4; r++) {
                float p = valid ? __expf(sc[kt][r] - mx[r]) : 0.f;
                sc[kt][r] = p;
                sum[r] += p;
            }
        }
#pragma unroll
        for (int off = 1; off < 16; off <<= 1)
#pragma unroll
            for (int r = 0; r < 4; r++) sum[r] += __shfl_xor(sum[r], off);
        float inv[4];
#pragma unroll
        for (int r = 0; r < 4; r++) inv[r] = 1.f / sum[r];
        unsigned short* Pw = PL + w * 16 * PSTR;
#pragma unroll
        for (int kt = 0; kt < KT; kt++) {
#pragma unroll
            for (int r = 0; r < 4; r++)
                Pw[(fq * 4 + r) * PSTR + kt * 16 + fr] = f2h(sc[kt][r] * inv[r]);
        }
        f32x4 o[4];
#pragma unroll
        for (int n = 0; n < 4; n++) o[n] = (f32x4)0.f;
#pragma unroll
        for (int ks = 0; ks < PVKT; ks++) {
            half8 pa = *(const half8*)(Pw + fr * PSTR + ks * 32 + fq * 8);
#pragma unroll
            for (int n = 0; n < 4; n++) {
                half8 vb = *(const half8*)(VT + (n * 16 + fr) * PSTR + ks * 32 + fq * 8);
                o[n] = __builtin_amdgcn_mfma_f32_16x16x32_f16(pa, vb, o[n], 0, 0, 0);
            }
        }
#pragma unroll
        for (int n = 0; n < 4; n++) {
#pragma unroll
            for (int r = 0; r < 4; r++) {
                int row = qt * 16 + fq * 4 + r;
                if (row < S) {
                    size_t oidx = ((size_t)b * S + row) * 768 + (size_t)h * 64 + n * 16 + fr;
                    oh[oidx] = f2h(o[n][r]);
                }
            }
        }
    }
}

// ---------------------------------------------------------------- prune machinery (fp32)
__global__ __launch_bounds__(256) void normsq_k(const float* __restrict__ x, float* __restrict__ norms)
{
    const float* xr = x + (size_t)blockIdx.x * 768;
    int t = threadIdx.x;
    float v0 = xr[t], v1 = xr[t + 256], v2 = xr[t + 512];
    float ss = v0 * v0 + v1 * v1 + v2 * v2;
#pragma unroll
    for (int o = 32; o; o >>= 1) ss += __shfl_xor(ss, o);
    __shared__ float r1[4];
    if ((t & 63) == 0) r1[t >> 6] = ss;
    __syncthreads();
    if (t == 0) norms[blockIdx.x] = r1[0] + r1[1] + r1[2] + r1[3];
}

__global__ __launch_bounds__(256) void topk_k(const float* __restrict__ norms,
                                              int* __restrict__ idxmap, int* __restrict__ cnt)
{
    int b = blockIdx.x, t = threadIdx.x;
    __shared__ float n[NTOK];
    __shared__ unsigned char kp[NTOK];
    if (t < NTOK) n[t] = norms[b * NTOK + t];
    __syncthreads();
    if (t < NTOK) {
        float me = n[t];
        int rank = 0;
        for (int j = 0; j < NTOK; j++) rank += (n[j] > me) || (n[j] == me && j < t);
        kp[t] = (rank < 98) || (t == 0);
    }
    __syncthreads();
    if (t == 0) {
        int c = 0;
        for (int s = 0; s < NTOK; s++) if (kp[s]) idxmap[b * SL + c++] = s;
        cnt[b] = c;
        for (int j = c; j < SL; j++) idxmap[b * SL + j] = 0;
    }
}

__global__ __launch_bounds__(256) void gather_k(const float* __restrict__ x, const int* __restrict__ idxmap,
                                                const int* __restrict__ cnt, float* __restrict__ xl)
{
    int j = blockIdx.x, b = blockIdx.y;
    size_t dst = ((size_t)b * SL + j) * 768;
    if (j < cnt[b]) {
        int s = idxmap[b * SL + j];
        size_t src = ((size_t)b * NTOK + s) * 768;
        for (int d = threadIdx.x; d < 768; d += 256) xl[dst + d] = x[src + d];
    } else {
        for (int d = threadIdx.x; d < 768; d += 256) xl[dst + d] = 0.f;
    }
}

// ---------------------------------------------------------------- launch
extern "C" void kernel_launch(void* const* d_in, const int* in_sizes, int n_in,
                              void* d_out, int out_size, void* d_ws, size_t ws_size,
                              hipStream_t stream)
{
    const float* images  = (const float*)d_in[0];
    const float* patch_w = (const float*)d_in[1];
    const float* patch_b = (const float*)d_in[2];
    const float* cls_tok = (const float*)d_in[3];
    const float* pos_emb = (const float*)d_in[4];
    const float* ln1_g   = (const float*)d_in[5];
    const float* ln1_b   = (const float*)d_in[6];
    const float* qkv_w   = (const float*)d_in[7];
    const float* qkv_b   = (const float*)d_in[8];
    const float* proj_w  = (const float*)d_in[9];
    const float* proj_b  = (const float*)d_in[10];
    const float* ln2_g   = (const float*)d_in[11];
    const float* ln2_b   = (const float*)d_in[12];
    const float* fc1_w   = (const float*)d_in[13];
    const float* fc1_b   = (const float*)d_in[14];
    const float* fc2_w   = (const float*)d_in[15];
    const float* fc2_b   = (const float*)d_in[16];
    const float* norm_g  = (const float*)d_in[17];
    const float* norm_b  = (const float*)d_in[18];
    const float* head_w  = (const float*)d_in[19];
    const float* head_b  = (const float*)d_in[20];
    float* outp = (float*)d_out;

    char* W = (char*)d_ws;
    float* x = (float*)W;                                       // 38,731,776 B
    unsigned short* hbh = (unsigned short*)(W + 38731776);      // LN/attn-out fp16
    char* R = W + 77463552;                                     // big region
    unsigned short* wbh = (unsigned short*)(W + 232390656);     // per-layer weights fp16
    unsigned short* pwh = (unsigned short*)(W + 260702208);     // patch_w fp16
    unsigned short* hwb = (unsigned short*)(W + 263061504);     // head_w fp16
    float* norms = (float*)(W + 264634368);
    unsigned short* clsb = (unsigned short*)(W + 264684800);
    int* idxmap = (int*)(W + 264881408);
    int* cnt    = (int*)(W + 264906752);

    unsigned short* ph  = (unsigned short*)R;                   // patches fp16
    float* emb = (float*)(R + 38535168);
    unsigned short* qkh = (unsigned short*)R;                   // qkv out fp16
    unsigned short* ffh = (unsigned short*)R;                   // fc1 out fp16
    float* xl = (float*)(R + 83886080);                         // late residual fp32

    const int LDS_EARLY = (64 * 232 + 4 * 16 * 232) * 2;   // 59,392
    const int LDS_LATE  = (64 * 136 + 4 * 16 * 136) * 2;   // 34,816
    const int LDS_G256  = 131072;
    (void)hipFuncSetAttribute(reinterpret_cast<const void*>(&attn2_k<197, 13, 7, 232>),
                              hipFuncAttributeMaxDynamicSharedMemorySize, LDS_EARLY);
    (void)hipFuncSetAttribute(reinterpret_cast<const void*>(&attn2_k<99, 7, 4, 136>),
                              hipFuncAttributeMaxDynamicSharedMemorySize, LDS_LATE);
    (void)hipFuncSetAttribute(reinterpret_cast<const void*>(&gemm256_k<0, 1>),
                              hipFuncAttributeMaxDynamicSharedMemorySize, LDS_G256);
    (void)hipFuncSetAttribute(reinterpret_cast<const void*>(&gemm256_k<1, 1>),
                              hipFuncAttributeMaxDynamicSharedMemorySize, LDS_G256);

    // 128-tile grids
    const int nR1 = 99, nRm1 = 13;     // M = 12608
    const int nRp = 98, nRmp = 13;     // patch M = 12544
    const int nR2 = 50, nRm2 = 7;      // M = 6336
    // 256-tile grids (used where blocks >= ~256)
    const int nR1q = 50, nR1qc = 7;    // M = 12608 in 256-rows
    const int nR2q = 25, nR2qc = 4;    // M = 6336 in 256-rows

    // ---- patch embed ----
    cvt_simple_k<<<576, 256, 0, stream>>>(patch_w, pwh, 147456);
    patch_extract2_k<<<dim3(196, NB), 256, 0, stream>>>(images, ph);
    mgemm_k<0, 0, 2><<<8 * nRmp * 6, 256, 0, stream>>>(ph, pwh, patch_b, nullptr,
        nullptr, emb, 12544, 768, 768, nRp, 6, nRmp);
    assemble_k<<<dim3(NTOK, NB), 256, 0, stream>>>(emb, cls_tok, pos_emb, x);

    const int M1 = NB * NTOK;   // 12608
    for (int i = 0; i < 4; i++) {
        cvt_layer_k<<<6912, 256, 0, stream>>>(qkv_w + (size_t)i * 1769472, proj_w + (size_t)i * 589824,
                                              fc1_w + (size_t)i * 2359296, fc2_w + (size_t)i * 2359296,
                                              wbh);
        ln2_k<<<M1, 256, 0, stream>>>(x, hbh, ln1_g + (size_t)i * 768, ln1_b + (size_t)i * 768, 768);
        gemm256_k<0, 1><<<8 * nR1qc * 9, 512, LDS_G256, stream>>>(hbh, wbh,
            qkv_b + (size_t)i * 2304, qkh, nullptr, M1, 2304, 768, nR1q, 9);
        attn2_k<197, 13, 7, 232><<<dim3(NHEAD, NB), 256, LDS_EARLY, stream>>>(qkh, hbh, nullptr);
        mgemm_k<2, 0, 2><<<8 * nRm1 * 6, 256, 0, stream>>>(hbh, wbh + 1769472,
            proj_b + (size_t)i * 768, x, nullptr, x, M1, 768, 768, nR1, 6, nRm1);
        ln2_k<<<M1, 256, 0, stream>>>(x, hbh, ln2_g + (size_t)i * 768, ln2_b + (size_t)i * 768, 768);
        gemm256_k<1, 1><<<8 * nR1qc * 12, 512, LDS_G256, stream>>>(hbh, wbh + 2359296,
            fc1_b + (size_t)i * 3072, ffh, nullptr, M1, 3072, 768, nR1q, 12);
        mgemm_k<2, 0, 2><<<8 * nRm1 * 6, 256, 0, stream>>>(ffh, wbh + 4718592,
            fc2_b + (size_t)i * 768, x, nullptr, x, M1, 768, 3072, nR1, 6, nRm1);
    }

    // ---- prune + compact ----
    normsq_k<<<M1, 256, 0, stream>>>(x, norms);
    topk_k<<<NB, 256, 0, stream>>>(norms, idxmap, cnt);
    gather_k<<<dim3(SL, NB), 256, 0, stream>>>(x, idxmap, cnt, xl);

    const int M2 = NB * SL;     // 6336
    for (int i = 4; i < 12; i++) {
        cvt_layer_k<<<6912, 256, 0, stream>>>(qkv_w + (size_t)i * 1769472, proj_w + (size_t)i * 589824,
                                              fc1_w + (size_t)i * 2359296, fc2_w + (size_t)i * 2359296,
                                              wbh);
        ln2_k<<<M2, 256, 0, stream>>>(xl, hbh, ln1_g + (size_t)i * 768, ln1_b + (size_t)i * 768, 768);
        gemm256_k<0, 1><<<8 * nR2qc * 9, 512, LDS_G256, stream>>>(hbh, wbh,
            qkv_b + (size_t)i * 2304, qkh, nullptr, M2, 2304, 768, nR2q, 9);
        attn2_k<99, 7, 4, 136><<<dim3(NHEAD, NB), 256, LDS_LATE, stream>>>(qkh, hbh, cnt);
        mgemm_k<2, 0, 2><<<8 * nRm2 * 6, 256, 0, stream>>>(hbh, wbh + 1769472,
            proj_b + (size_t)i * 768, xl, nullptr, xl, M2, 768, 768, nR2, 6, nRm2);
        ln2_k<<<M2, 256, 0, stream>>>(xl, hbh, ln2_g + (size_t)i * 768, ln2_b + (size_t)i * 768, 768);
        gemm256_k<1, 1><<<8 * nR2qc * 12, 512, LDS_G256, stream>>>(hbh, wbh + 2359296,
            fc1_b + (size_t)i * 3072, ffh, nullptr, M2, 3072, 768, nR2q, 12);
        mgemm_k<2, 0, 2><<<8 * nRm2 * 6, 256, 0, stream>>>(ffh, wbh + 4718592,
            fc2_b + (size_t)i * 768, xl, nullptr, xl, M2, 768, 3072, nR2, 6, nRm2);
    }

    // ---- final LN(CLS) + head ----
    ln2_k<<<NB, 256, 0, stream>>>(xl, clsb, norm_g, norm_b, (size_t)SL * 768);
    cvt_simple_k<<<750, 256, 0, stream>>>(head_w, hwb, 192000);
    mgemm_k<0, 0, 0><<<8, 256, 0, stream>>>(clsb, hwb,
        head_b, nullptr, nullptr, outp, 64, 1000, 768, 1, 8, 1);
}

// Round 9
// 3865.899 us; speedup vs baseline: 1.1930x; 1.1930x over previous
//
#include <hip/hip_runtime.h>
#include <cstdint>
#include <cstddef>

// ViT-B/16 + token pruning. Round 9: fp16 everywhere + fp16 residual stream.
// mgemm rebuilt with ring-3 LDS slots (48KB): counted vmcnt(4) + ONE barrier
// per K-tile and NO in-loop lgkmcnt/sched_barrier fences -> compiler emits
// fine-grained lgkmcnt interleave of ds_read with MFMA (m97 behavior).
// Slot safety: stage(t+2) writes slot (t+2)%3, whose iter-(t-1) reads retired
// before barrier t (reads precede that wave's MFMAs which precede the barrier).

#define NTOK 197
#define NB 64
#define NHEAD 12
#define SL 99

typedef __attribute__((ext_vector_type(8))) _Float16 half8;
typedef __attribute__((ext_vector_type(4))) float f32x4;
typedef __attribute__((ext_vector_type(4))) unsigned short us4;

#define DEV static __device__ __forceinline__

DEV unsigned short f2h(float f) {
    union { _Float16 h; unsigned short u; } v;
    v.h = (_Float16)f;
    return v.u;
}
DEV float h2f(unsigned short u) {
    union { _Float16 h; unsigned short u; } v;
    v.u = u;
    return (float)v.h;
}

DEV void gload16(const void* g, void* l) {
    __builtin_amdgcn_global_load_lds((const __attribute__((address_space(1))) unsigned int*)g,
                                     (__attribute__((address_space(3))) unsigned int*)l, 16, 0, 0);
}

// ---------------------------------------------------------------- weight conversion (fp32 -> fp16)
__global__ __launch_bounds__(256) void cvt_layer_k(const float* __restrict__ qw,
                                                   const float* __restrict__ pw,
                                                   const float* __restrict__ f1,
                                                   const float* __restrict__ f2,
                                                   unsigned short* __restrict__ dh)
{
    size_t t = (size_t)blockIdx.x * 256 + threadIdx.x;
    size_t e = t * 4;
    const float* src; size_t loc;
    if (e < 1769472)      { src = qw; loc = e; }
    else if (e < 2359296) { src = pw; loc = e - 1769472; }
    else if (e < 4718592) { src = f1; loc = e - 2359296; }
    else                  { src = f2; loc = e - 4718592; }
    float4 v = *(const float4*)(src + loc);
    us4 hi; hi.x = f2h(v.x); hi.y = f2h(v.y); hi.z = f2h(v.z); hi.w = f2h(v.w);
    *(us4*)(dh + e) = hi;
}

__global__ __launch_bounds__(256) void cvt_simple_k(const float* __restrict__ src,
                                                    unsigned short* __restrict__ dh, int n4)
{
    int t = blockIdx.x * 256 + threadIdx.x;
    if (t >= n4) return;
    size_t e = (size_t)t * 4;
    float4 v = *(const float4*)(src + e);
    us4 hi; hi.x = f2h(v.x); hi.y = f2h(v.y); hi.z = f2h(v.z); hi.w = f2h(v.w);
    *(us4*)(dh + e) = hi;
}

// ---------------------------------------------------------------- patch extract (fp32 -> fp16)
__global__ __launch_bounds__(256) void patch_extract2_k(const float* __restrict__ img,
                                                        unsigned short* __restrict__ ph)
{
    int pi = blockIdx.x, b = blockIdx.y;
    int gy = pi / 14, gx = pi % 14;
    size_t obase = ((size_t)b * 196 + pi) * 768;
    for (int f = threadIdx.x; f < 768; f += 256) {
        int c = f >> 8, py = (f >> 4) & 15, px = f & 15;
        float v = img[(((size_t)b * 3 + c) * 224 + gy * 16 + py) * 224 + gx * 16 + px];
        ph[obase + f] = f2h(v);
    }
}

// x[b,s,:] (fp16) = (s==0 ? cls : emb[b,s-1]) + pos[s]
__global__ __launch_bounds__(256) void assemble_k(const unsigned short* __restrict__ emb,
                                                  const float* __restrict__ cls,
                                                  const float* __restrict__ pos,
                                                  unsigned short* __restrict__ x)
{
    int s = blockIdx.x, b = blockIdx.y;
    size_t xo = ((size_t)b * NTOK + s) * 768;
    for (int d = threadIdx.x; d < 768; d += 256) {
        float v = (s == 0) ? cls[d] : h2f(emb[((size_t)b * 196 + (s - 1)) * 768 + d]);
        x[xo + d] = f2h(v + pos[(size_t)s * 768 + d]);
    }
}

// ---------------------------------------------------------------- layernorm fp16 -> fp16
__global__ __launch_bounds__(256) void ln2_k(const unsigned short* __restrict__ in,
                                             unsigned short* __restrict__ outh,
                                             const float* __restrict__ g,
                                             const float* __restrict__ bt, size_t ldin)
{
    const unsigned short* xr = in + (size_t)blockIdx.x * ldin;
    size_t ob = (size_t)blockIdx.x * 768;
    int t = threadIdx.x;
    float v0 = h2f(xr[t]), v1 = h2f(xr[t + 256]), v2 = h2f(xr[t + 512]);
    float s = v0 + v1 + v2;
#pragma unroll
    for (int o = 32; o; o >>= 1) s += __shfl_xor(s, o);
    __shared__ float r1[4], r2[4];
    int wv = t >> 6, ln = t & 63;
    if (ln == 0) r1[wv] = s;
    __syncthreads();
    float mean = (r1[0] + r1[1] + r1[2] + r1[3]) * (1.f / 768.f);
    float d0 = v0 - mean, d1 = v1 - mean, d2 = v2 - mean;
    float ss = d0 * d0 + d1 * d1 + d2 * d2;
#pragma unroll
    for (int o = 32; o; o >>= 1) ss += __shfl_xor(ss, o);
    if (ln == 0) r2[wv] = ss;
    __syncthreads();
    float inv = rsqrtf((r2[0] + r2[1] + r2[2] + r2[3]) * (1.f / 768.f) + 1e-6f);
    outh[ob + t]       = f2h(d0 * inv * g[t]       + bt[t]);
    outh[ob + t + 256] = f2h(d1 * inv * g[t + 256] + bt[t + 256]);
    outh[ob + t + 512] = f2h(d2 * inv * g[t + 512] + bt[t + 512]);
}

// ---------------------------------------------------------------- 128x128 fp16 MFMA GEMM, ring-3 pipeline
// A[M,K], W[N,K] fp16. EPI: 0 none, 1 GELU, 2 +res(fp16). OS: 0 fp32 out, 1 fp16 out.
// MAP: 0 linear, 1 xcd rows-fastest, 2 xcd cols-fastest.
template<int EPI, int OS, int MAP>
__global__ __launch_bounds__(256) void mgemm_k(const unsigned short* __restrict__ Ah,
                                               const unsigned short* __restrict__ Wh,
                                               const float* __restrict__ bias,
                                               const unsigned short* __restrict__ res,
                                               unsigned short* __restrict__ Chi,
                                               float* __restrict__ Cf,
                                               int M, int N, int K, int nR, int nC, int nRmax)
{
    __shared__ unsigned short lds[3 * 8192];   // 3 slots x (A 8KB + B 8KB) = 48 KiB

    int rt, ct;
    {
        int bid = blockIdx.x;
        if (MAP == 0) { rt = bid % nR; ct = bid / nR; }
        else {
            int x = bid & 7, u = bid >> 3, rl, c;
            if (MAP == 2) { c = u % nC; rl = u / nC; }
            else          { rl = u % nRmax; c = u / nRmax; }
            rt = x + 8 * rl; ct = c;
            if (rt >= nR) return;
        }
    }
    const int row0 = rt << 7, col0 = ct << 7;
    const int tid = threadIdx.x;
    const int w = tid >> 6, lane = tid & 63;
    const int wr = w >> 1, wc = w & 1;
    const int srow = lane >> 2;
    const int schunk = ((lane & 3) ^ ((srow >> 1) & 3)) << 3;   // pre-swizzled source chunk
    const int fr = lane & 15, fq = lane >> 4;
    const int rchunk = (fq ^ ((fr >> 1) & 3)) << 3;             // swizzled read chunk

    f32x4 acc[4][4];
#pragma unroll
    for (int m = 0; m < 4; m++)
#pragma unroll
        for (int n = 0; n < 4; n++) acc[m][n] = (f32x4)0.f;

    const int nk = K >> 5;

    auto stage = [&](int t, int slot) {
        const int k0 = t << 5;
        unsigned short* Ad = lds + slot * 8192;
        unsigned short* Bd = Ad + 4096;
#pragma unroll
        for (int i = 0; i < 2; i++) {
            int r = i * 64 + w * 16 + srow;
            int ga = row0 + r; if (ga > M - 1) ga = M - 1;
            int gb = col0 + r; if (gb > N - 1) gb = N - 1;
            gload16(Ah + (size_t)ga * K + k0 + schunk, Ad + i * 2048 + w * 512);
            gload16(Wh + (size_t)gb * K + k0 + schunk, Bd + i * 2048 + w * 512);
        }
    };

    stage(0, 0);
    stage(1, 1);
    int slot = 0, slot2 = 2;       // slot of tile t; slot of tile t+2
    for (int t = 0; t < nk; ++t) {
        if (t + 1 < nk) asm volatile("s_waitcnt vmcnt(4)" ::: "memory");
        else            asm volatile("s_waitcnt vmcnt(0)" ::: "memory");
        __builtin_amdgcn_s_barrier();              // slot `slot` fully staged everywhere
        if (t + 2 < nk) stage(t + 2, slot2);       // distinct slot: its readers retired pre-barrier
        const unsigned short* Ab = lds + slot * 8192;
        const unsigned short* Bb = Ab + 4096;
        half8 a[4], bb[4];
#pragma unroll
        for (int m = 0; m < 4; m++)
            a[m] = *(const half8*)(Ab + (wr * 64 + m * 16 + fr) * 32 + rchunk);
#pragma unroll
        for (int n = 0; n < 4; n++)
            bb[n] = *(const half8*)(Bb + (wc * 64 + n * 16 + fr) * 32 + rchunk);
        // no fences: compiler interleaves MFMA with fine-grained lgkmcnt
#pragma unroll
        for (int m = 0; m < 4; m++)
#pragma unroll
            for (int n = 0; n < 4; n++)
                acc[m][n] = __builtin_amdgcn_mfma_f32_16x16x32_f16(a[m], bb[n], acc[m][n], 0, 0, 0);
        slot = (slot == 2) ? 0 : slot + 1;
        slot2 = (slot2 == 2) ? 0 : slot2 + 1;
    }

#pragma unroll
    for (int m = 0; m < 4; m++) {
#pragma unroll
        for (int n = 0; n < 4; n++) {
            int col = col0 + wc * 64 + n * 16 + fr;
#pragma unroll
            for (int r = 0; r < 4; r++) {
                int row = row0 + wr * 64 + m * 16 + fq * 4 + r;
                if (row < M && col < N) {
                    float v = acc[m][n][r] + bias[col];
                    size_t o = (size_t)row * N + col;
                    if (EPI == 2) v += h2f(res[o]);
                    if (EPI == 1) v = 0.5f * v * (1.f + erff(v * 0.70710678118654752f));
                    if (OS == 0) Cf[o] = v;
                    else Chi[o] = f2h(v);
                }
            }
        }
    }
}

// ---------------------------------------------------------------- fused MFMA attention (fp16)
template<int S, int KT, int PVKT, int PSTR>
__global__ __launch_bounds__(256) void attn2_k(const unsigned short* __restrict__ qh,
                                               unsigned short* __restrict__ oh,
                                               const int* __restrict__ cntp)
{
    constexpr int PVK = PVKT * 32;
    constexpr int QT = (S + 15) / 16;
    extern __shared__ unsigned short sh[];
    unsigned short* VT = sh;                 // [64][PSTR]  V^T
    unsigned short* PL = sh + 64 * PSTR;     // 4 waves x [16][PSTR]

    const int h = blockIdx.x, b = blockIdx.y;
    const int tid = threadIdx.x, w = tid >> 6, lane = tid & 63;
    const int nk = cntp ? cntp[b] : S;
    const size_t qbase = (size_t)b * S * 2304 + (size_t)h * 64;
    const int fr = lane & 15, fq = lane >> 4;

    for (int j0 = 0; j0 < S; j0 += 32) {
        int j = j0 + (tid >> 3);
        int d8 = (tid & 7) * 8;
        if (j < S) {
            size_t src = qbase + (size_t)j * 2304 + 1536 + d8;
            us4 v0 = *(const us4*)(qh + src);
            us4 v1 = *(const us4*)(qh + src + 4);
            VT[(d8 + 0) * PSTR + j] = v0.x; VT[(d8 + 1) * PSTR + j] = v0.y;
            VT[(d8 + 2) * PSTR + j] = v0.z; VT[(d8 + 3) * PSTR + j] = v0.w;
            VT[(d8 + 4) * PSTR + j] = v1.x; VT[(d8 + 5) * PSTR + j] = v1.y;
            VT[(d8 + 6) * PSTR + j] = v1.z; VT[(d8 + 7) * PSTR + j] = v1.w;
        }
    }
    for (int idx = tid; idx < 64 * (PVK - S); idx += 256) {
        int d = idx / (PVK - S), j = S + idx % (PVK - S);
        VT[d * PSTR + j] = 0;
    }
    {
        unsigned short* Pw = PL + w * 16 * PSTR;
        for (int idx = lane; idx < 16 * (PVK - 16 * KT); idx += 64) {
            int rr = idx / (PVK - 16 * KT), cc = 16 * KT + idx % (PVK - 16 * KT);
            Pw[rr * PSTR + cc] = 0;
        }
    }
    __syncthreads();

    for (int qt = w; qt < QT; qt += 4) {
        int qr = qt * 16 + fr; int qrc = qr < S ? qr : S - 1;
        const size_t qrow = qbase + (size_t)qrc * 2304;
        half8 qf0[2];
#pragma unroll
        for (int ks = 0; ks < 2; ks++)
            qf0[ks] = *(const half8*)(qh + qrow + ks * 32 + fq * 8);
        f32x4 sc[KT];
#pragma unroll
        for (int kt = 0; kt < KT; kt++) {
            int ky = kt * 16 + fr; int kyc = ky < S ? ky : S - 1;
            const size_t krow = qbase + (size_t)kyc * 2304 + 768;
            f32x4 acc = (f32x4)0.f;
#pragma unroll
            for (int ks = 0; ks < 2; ks++) {
                half8 kh = *(const half8*)(qh + krow + ks * 32 + fq * 8);
                acc = __builtin_amdgcn_mfma_f32_16x16x32_f16(qf0[ks], kh, acc, 0, 0, 0);
            }
            sc[kt] = acc;
        }
        float mx[4] = {-3e38f, -3e38f, -3e38f, -3e38f};
#pragma unroll
        for (int kt = 0; kt < KT; kt++) {
            bool valid = (kt * 16 + fr) < nk;
#pragma unroll
            for (int r = 0; r < 4; r++) {
                float s = sc[kt][r] * 0.125f;
                sc[kt][r] = s;
                if (valid) mx[r] = fmaxf(mx[r], s);
            }
        }
#pragma unroll
        for (int off = 1; off < 16; off <<= 1)
#pragma unroll
            for (int r = 0; r < 4; r++) mx[r] = fmaxf(mx[r], __shfl_xor(mx[r], off));
        float sum[4] = {0.f, 0.f, 0.f, 0.f};
#pragma unroll
        for (int kt = 0; kt < KT; kt++) {
            bool valid = (kt * 16 + fr) < nk;
#pragma unroll
            for (int r = 0; r < 4; r++) {
                float p = valid ? __expf(sc[kt][r] - mx[r]) : 0.f;
                sc[kt][r] = p;
                sum[r] += p;
            }
        }
#pragma unroll
        for (int off = 1; off < 16; off <<= 1)
#pragma unroll
            for (int r = 0; r < 4; r++) sum[r] += __shfl_xor(sum[r], off);
        float inv[4];
#pragma unroll
        for (int r = 0; r < 4; r++) inv[r] = 1.f / sum[r];
        unsigned short* Pw = PL + w * 16 * PSTR;
#pragma unroll
        for (int kt = 0; kt < KT; kt++) {
#pragma unroll
            for (int r = 0; r < 4; r++)
                Pw[(fq * 4 + r) * PSTR + kt * 16 + fr] = f2h(sc[kt][r] * inv[r]);
        }
        f32x4 o[4];
#pragma unroll
        for (int n = 0; n < 4; n++) o[n] = (f32x4)0.f;
#pragma unroll
        for (int ks = 0; ks < PVKT; ks++) {
            half8 pa = *(const half8*)(Pw + fr * PSTR + ks * 32 + fq * 8);
#pragma unroll
            for (int n = 0; n < 4; n++) {
                half8 vb = *(const half8*)(VT + (n * 16 + fr) * PSTR + ks * 32 + fq * 8);
                o[n] = __builtin_amdgcn_mfma_f32_16x16x32_f16(pa, vb, o[n], 0, 0, 0);
            }
        }
#pragma unroll
        for (int n = 0; n < 4; n++) {
#pragma unroll
            for (int r = 0; r < 4; r++) {
                int row = qt * 16 + fq * 4 + r;
                if (row < S) {
                    size_t oidx = ((size_t)b * S + row) * 768 + (size_t)h * 64 + n * 16 + fr;
                    oh[oidx] = f2h(o[n][r]);
                }
            }
        }
    }
}

// ---------------------------------------------------------------- prune machinery (fp16 in)
__global__ __launch_bounds__(256) void normsq_k(const unsigned short* __restrict__ x,
                                                float* __restrict__ norms)
{
    const unsigned short* xr = x + (size_t)blockIdx.x * 768;
    int t = threadIdx.x;
    float v0 = h2f(xr[t]), v1 = h2f(xr[t + 256]), v2 = h2f(xr[t + 512]);
    float ss = v0 * v0 + v1 * v1 + v2 * v2;
#pragma unroll
    for (int o = 32; o; o >>= 1) ss += __shfl_xor(ss, o);
    __shared__ float r1[4];
    if ((t & 63) == 0) r1[t >> 6] = ss;
    __syncthreads();
    if (t == 0) norms[blockIdx.x] = r1[0] + r1[1] + r1[2] + r1[3];
}

__global__ __launch_bounds__(256) void topk_k(const float* __restrict__ norms,
                                              int* __restrict__ idxmap, int* __restrict__ cnt)
{
    int b = blockIdx.x, t = threadIdx.x;
    __shared__ float n[NTOK];
    __shared__ unsigned char kp[NTOK];
    if (t < NTOK) n[t] = norms[b * NTOK + t];
    __syncthreads();
    if (t < NTOK) {
        float me = n[t];
        int rank = 0;
        for (int j = 0; j < NTOK; j++) rank += (n[j] > me) || (n[j] == me && j < t);
        kp[t] = (rank < 98) || (t == 0);
    }
    __syncthreads();
    if (t == 0) {
        int c = 0;
        for (int s = 0; s < NTOK; s++) if (kp[s]) idxmap[b * SL + c++] = s;
        cnt[b] = c;
        for (int j = c; j < SL; j++) idxmap[b * SL + j] = 0;
    }
}

__global__ __launch_bounds__(256) void gather_k(const unsigned short* __restrict__ x,
                                                const int* __restrict__ idxmap,
                                                const int* __restrict__ cnt,
                                                unsigned short* __restrict__ xl)
{
    int j = blockIdx.x, b = blockIdx.y;
    size_t dst = ((size_t)b * SL + j) * 768;
    if (j < cnt[b]) {
        int s = idxmap[b * SL + j];
        size_t src = ((size_t)b * NTOK + s) * 768;
        for (int d = threadIdx.x; d < 768; d += 256) xl[dst + d] = x[src + d];
    } else {
        for (int d = threadIdx.x; d < 768; d += 256) xl[dst + d] = 0;
    }
}

// ---------------------------------------------------------------- launch
extern "C" void kernel_launch(void* const* d_in, const int* in_sizes, int n_in,
                              void* d_out, int out_size, void* d_ws, size_t ws_size,
                              hipStream_t stream)
{
    const float* images  = (const float*)d_in[0];
    const float* patch_w = (const float*)d_in[1];
    const float* patch_b = (const float*)d_in[2];
    const float* cls_tok = (const float*)d_in[3];
    const float* pos_emb = (const float*)d_in[4];
    const float* ln1_g   = (const float*)d_in[5];
    const float* ln1_b   = (const float*)d_in[6];
    const float* qkv_w   = (const float*)d_in[7];
    const float* qkv_b   = (const float*)d_in[8];
    const float* proj_w  = (const float*)d_in[9];
    const float* proj_b  = (const float*)d_in[10];
    const float* ln2_g   = (const float*)d_in[11];
    const float* ln2_b   = (const float*)d_in[12];
    const float* fc1_w   = (const float*)d_in[13];
    const float* fc1_b   = (const float*)d_in[14];
    const float* fc2_w   = (const float*)d_in[15];
    const float* fc2_b   = (const float*)d_in[16];
    const float* norm_g  = (const float*)d_in[17];
    const float* norm_b  = (const float*)d_in[18];
    const float* head_w  = (const float*)d_in[19];
    const float* head_b  = (const float*)d_in[20];
    float* outp = (float*)d_out;

    // -------- workspace layout (bytes), all fp16 activations. total ~143 MB --------
    char* W = (char*)d_ws;
    unsigned short* x16  = (unsigned short*)W;                   // 19,365,888
    unsigned short* hbh  = (unsigned short*)(W + 19365888);      // 19,365,888
    char* R = W + 38731776;                                      // 77,463,552 shared region
    unsigned short* ph   = (unsigned short*)R;                   // patches [12544*768]
    unsigned short* emb  = (unsigned short*)(R + 19365888);      // patch-GEMM out fp16
    unsigned short* qkh  = (unsigned short*)R;                   // qkv out
    unsigned short* ffh  = (unsigned short*)R;                   // fc1 out
    unsigned short* xl16 = (unsigned short*)(W + 116195328);     // 9,732,096
    unsigned short* wbh  = (unsigned short*)(W + 125927424);     // 14,155,776 per-layer weights
    unsigned short* pwh  = (unsigned short*)(W + 140083200);     // patch_w fp16
    unsigned short* hwb  = (unsigned short*)(W + 141262848);     // head_w fp16 (1024x768)
    float* norms         = (float*)(W + 142835712);
    unsigned short* clsb = (unsigned short*)(W + 142886912);     // 64x768 fp16
    int* idxmap          = (int*)(W + 142985216);
    int* cnt             = (int*)(W + 143010560);

    const int LDS_EARLY = (64 * 232 + 4 * 16 * 232) * 2;   // 59,392
    const int LDS_LATE  = (64 * 136 + 4 * 16 * 136) * 2;   // 34,816
    (void)hipFuncSetAttribute(reinterpret_cast<const void*>(&attn2_k<197, 13, 7, 232>),
                              hipFuncAttributeMaxDynamicSharedMemorySize, LDS_EARLY);
    (void)hipFuncSetAttribute(reinterpret_cast<const void*>(&attn2_k<99, 7, 4, 136>),
                              hipFuncAttributeMaxDynamicSharedMemorySize, LDS_LATE);

    const int nR1 = 99, nRm1 = 13;     // M = 12608 in 128-rows
    const int nRp = 98, nRmp = 13;     // patch M = 12544
    const int nR2 = 50, nRm2 = 7;      // M = 6336

    // ---- patch embed ----
    cvt_simple_k<<<576, 256, 0, stream>>>(patch_w, pwh, 147456);
    patch_extract2_k<<<dim3(196, NB), 256, 0, stream>>>(images, ph);
    mgemm_k<0, 1, 2><<<8 * nRmp * 6, 256, 0, stream>>>(ph, pwh, patch_b, nullptr,
        emb, nullptr, 12544, 768, 768, nRp, 6, nRmp);
    assemble_k<<<dim3(NTOK, NB), 256, 0, stream>>>(emb, cls_tok, pos_emb, x16);

    const int M1 = NB * NTOK;   // 12608
    for (int i = 0; i < 4; i++) {
        cvt_layer_k<<<6912, 256, 0, stream>>>(qkv_w + (size_t)i * 1769472, proj_w + (size_t)i * 589824,
                                              fc1_w + (size_t)i * 2359296, fc2_w + (size_t)i * 2359296,
                                              wbh);
        ln2_k<<<M1, 256, 0, stream>>>(x16, hbh, ln1_g + (size_t)i * 768, ln1_b + (size_t)i * 768, 768);
        mgemm_k<0, 1, 1><<<8 * nRm1 * 18, 256, 0, stream>>>(hbh, wbh,
            qkv_b + (size_t)i * 2304, nullptr, qkh, nullptr, M1, 2304, 768, nR1, 18, nRm1);
        attn2_k<197, 13, 7, 232><<<dim3(NHEAD, NB), 256, LDS_EARLY, stream>>>(qkh, hbh, nullptr);
        mgemm_k<2, 1, 2><<<8 * nRm1 * 6, 256, 0, stream>>>(hbh, wbh + 1769472,
            proj_b + (size_t)i * 768, x16, x16, nullptr, M1, 768, 768, nR1, 6, nRm1);
        ln2_k<<<M1, 256, 0, stream>>>(x16, hbh, ln2_g + (size_t)i * 768, ln2_b + (size_t)i * 768, 768);
        mgemm_k<1, 1, 1><<<8 * nRm1 * 24, 256, 0, stream>>>(hbh, wbh + 2359296,
            fc1_b + (size_t)i * 3072, nullptr, ffh, nullptr, M1, 3072, 768, nR1, 24, nRm1);
        mgemm_k<2, 1, 2><<<8 * nRm1 * 6, 256, 0, stream>>>(ffh, wbh + 4718592,
            fc2_b + (size_t)i * 768, x16, x16, nullptr, M1, 768, 3072, nR1, 6, nRm1);
    }

    // ---- prune + compact ----
    normsq_k<<<M1, 256, 0, stream>>>(x16, norms);
    topk_k<<<NB, 256, 0, stream>>>(norms, idxmap, cnt);
    gather_k<<<dim3(SL, NB), 256, 0, stream>>>(x16, idxmap, cnt, xl16);

    const int M2 = NB * SL;     // 6336
    for (int i = 4; i < 12; i++) {
        cvt_layer_k<<<6912, 256, 0, stream>>>(qkv_w + (size_t)i * 1769472, proj_w + (size_t)i * 589824,
                                              fc1_w + (size_t)i * 2359296, fc2_w + (size_t)i * 2359296,
                                              wbh);
        ln2_k<<<M2, 256, 0, stream>>>(xl16, hbh, ln1_g + (size_t)i * 768, ln1_b + (size_t)i * 768, 768);
        mgemm_k<0, 1, 1><<<8 * nRm2 * 18, 256, 0, stream>>>(hbh, wbh,
            qkv_b + (size_t)i * 2304, nullptr, qkh, nullptr, M2, 2304, 768, nR2, 18, nRm2);
        attn2_k<99, 7, 4, 136><<<dim3(NHEAD, NB), 256, LDS_LATE, stream>>>(qkh, hbh, cnt);
        mgemm_k<2, 1, 2><<<8 * nRm2 * 6, 256, 0, stream>>>(hbh, wbh + 1769472,
            proj_b + (size_t)i * 768, xl16, xl16, nullptr, M2, 768, 768, nR2, 6, nRm2);
        ln2_k<<<M2, 256, 0, stream>>>(xl16, hbh, ln2_g + (size_t)i * 768, ln2_b + (size_t)i * 768, 768);
        mgemm_k<1, 1, 1><<<8 * nRm2 * 24, 256, 0, stream>>>(hbh, wbh + 2359296,
            fc1_b + (size_t)i * 3072, nullptr, ffh, nullptr, M2, 3072, 768, nR2, 24, nRm2);
        mgemm_k<2, 1, 2><<<8 * nRm2 * 6, 256, 0, stream>>>(ffh, wbh + 4718592,
            fc2_b + (size_t)i * 768, xl16, xl16, nullptr, M2, 768, 3072, nR2, 6, nRm2);
    }

    // ---- final LN(CLS) + head ----
    ln2_k<<<NB, 256, 0, stream>>>(xl16, clsb, norm_g, norm_b, (size_t)SL * 768);
    cvt_simple_k<<<750, 256, 0, stream>>>(head_w, hwb, 192000);
    mgemm_k<0, 0, 0><<<8, 256, 0, stream>>>(clsb, hwb,
        head_b, nullptr, nullptr, outp, 64, 1000, 768, 1, 8, 1);
}

// Round 10
// 3845.652 us; speedup vs baseline: 1.1993x; 1.0053x over previous
//
#include <hip/hip_runtime.h>
#include <cstdint>
#include <cstddef>

// ViT-B/16 + token pruning. Round 10: chunked-XCD GEMM block mapping.
// R9 diagnosis: GEMMs stage ~7 TB/s of VMEM traffic, 92% from L3 (A panel
// re-read per column tile because mod-8 row interleave spreads A over all
// XCDs). Fix: XCD gets a CONTIGUOUS row chunk (2.4 MB, fits 4MB L2);
// rows-fastest within chunk (MAP3) keeps A L2-resident; fc2 (A too big)
// uses cols-fastest within chunk (MAP4) for A row-tile reuse.
// Weight conversion batched 4 layers/launch.

#define NTOK 197
#define NB 64
#define NHEAD 12
#define SL 99

typedef __attribute__((ext_vector_type(8))) _Float16 half8;
typedef __attribute__((ext_vector_type(4))) float f32x4;
typedef __attribute__((ext_vector_type(4))) unsigned short us4;

#define DEV static __device__ __forceinline__

DEV unsigned short f2h(float f) {
    union { _Float16 h; unsigned short u; } v;
    v.h = (_Float16)f;
    return v.u;
}
DEV float h2f(unsigned short u) {
    union { _Float16 h; unsigned short u; } v;
    v.u = u;
    return (float)v.h;
}

DEV void gload16(const void* g, void* l) {
    __builtin_amdgcn_global_load_lds((const __attribute__((address_space(1))) unsigned int*)g,
                                     (__attribute__((address_space(3))) unsigned int*)l, 16, 0, 0);
}

// ---------------------------------------------------------------- weight conversion (4 layers / launch)
__global__ __launch_bounds__(256) void cvt_layer4_k(const float* __restrict__ qw,
                                                    const float* __restrict__ pw,
                                                    const float* __restrict__ f1,
                                                    const float* __restrict__ f2,
                                                    int i0,
                                                    unsigned short* __restrict__ dst)
{
    int l = blockIdx.x / 6912;                 // 0..3 within group
    int b2 = blockIdx.x % 6912;
    int li = i0 + l;                           // absolute layer
    size_t t = (size_t)b2 * 256 + threadIdx.x; // < 1769472
    size_t e = t * 4;
    const float* src; size_t loc;
    if (e < 1769472)      { src = qw + (size_t)li * 1769472; loc = e; }
    else if (e < 2359296) { src = pw + (size_t)li * 589824;  loc = e - 1769472; }
    else if (e < 4718592) { src = f1 + (size_t)li * 2359296; loc = e - 2359296; }
    else                  { src = f2 + (size_t)li * 2359296; loc = e - 4718592; }
    float4 v = *(const float4*)(src + loc);
    us4 hi; hi.x = f2h(v.x); hi.y = f2h(v.y); hi.z = f2h(v.z); hi.w = f2h(v.w);
    *(us4*)(dst + (size_t)l * 7077888 + e) = hi;
}

__global__ __launch_bounds__(256) void cvt_simple_k(const float* __restrict__ src,
                                                    unsigned short* __restrict__ dh, int n4)
{
    int t = blockIdx.x * 256 + threadIdx.x;
    if (t >= n4) return;
    size_t e = (size_t)t * 4;
    float4 v = *(const float4*)(src + e);
    us4 hi; hi.x = f2h(v.x); hi.y = f2h(v.y); hi.z = f2h(v.z); hi.w = f2h(v.w);
    *(us4*)(dh + e) = hi;
}

// ---------------------------------------------------------------- patch extract (fp32 -> fp16)
__global__ __launch_bounds__(256) void patch_extract2_k(const float* __restrict__ img,
                                                        unsigned short* __restrict__ ph)
{
    int pi = blockIdx.x, b = blockIdx.y;
    int gy = pi / 14, gx = pi % 14;
    size_t obase = ((size_t)b * 196 + pi) * 768;
    for (int f = threadIdx.x; f < 768; f += 256) {
        int c = f >> 8, py = (f >> 4) & 15, px = f & 15;
        float v = img[(((size_t)b * 3 + c) * 224 + gy * 16 + py) * 224 + gx * 16 + px];
        ph[obase + f] = f2h(v);
    }
}

__global__ __launch_bounds__(256) void assemble_k(const unsigned short* __restrict__ emb,
                                                  const float* __restrict__ cls,
                                                  const float* __restrict__ pos,
                                                  unsigned short* __restrict__ x)
{
    int s = blockIdx.x, b = blockIdx.y;
    size_t xo = ((size_t)b * NTOK + s) * 768;
    for (int d = threadIdx.x; d < 768; d += 256) {
        float v = (s == 0) ? cls[d] : h2f(emb[((size_t)b * 196 + (s - 1)) * 768 + d]);
        x[xo + d] = f2h(v + pos[(size_t)s * 768 + d]);
    }
}

// ---------------------------------------------------------------- layernorm fp16 -> fp16
__global__ __launch_bounds__(256) void ln2_k(const unsigned short* __restrict__ in,
                                             unsigned short* __restrict__ outh,
                                             const float* __restrict__ g,
                                             const float* __restrict__ bt, size_t ldin)
{
    const unsigned short* xr = in + (size_t)blockIdx.x * ldin;
    size_t ob = (size_t)blockIdx.x * 768;
    int t = threadIdx.x;
    float v0 = h2f(xr[t]), v1 = h2f(xr[t + 256]), v2 = h2f(xr[t + 512]);
    float s = v0 + v1 + v2;
#pragma unroll
    for (int o = 32; o; o >>= 1) s += __shfl_xor(s, o);
    __shared__ float r1[4], r2[4];
    int wv = t >> 6, ln = t & 63;
    if (ln == 0) r1[wv] = s;
    __syncthreads();
    float mean = (r1[0] + r1[1] + r1[2] + r1[3]) * (1.f / 768.f);
    float d0 = v0 - mean, d1 = v1 - mean, d2 = v2 - mean;
    float ss = d0 * d0 + d1 * d1 + d2 * d2;
#pragma unroll
    for (int o = 32; o; o >>= 1) ss += __shfl_xor(ss, o);
    if (ln == 0) r2[wv] = ss;
    __syncthreads();
    float inv = rsqrtf((r2[0] + r2[1] + r2[2] + r2[3]) * (1.f / 768.f) + 1e-6f);
    outh[ob + t]       = f2h(d0 * inv * g[t]       + bt[t]);
    outh[ob + t + 256] = f2h(d1 * inv * g[t + 256] + bt[t + 256]);
    outh[ob + t + 512] = f2h(d2 * inv * g[t + 512] + bt[t + 512]);
}

// ---------------------------------------------------------------- 128x128 fp16 MFMA GEMM, ring-3 pipeline
// A[M,K], W[N,K] fp16. EPI: 0 none, 1 GELU, 2 +res(fp16). OS: 0 fp32 out, 1 fp16 out.
// MAP: 0 linear; 3 chunked-XCD rows-fastest-within-chunk (A-chunk L2-resident);
//      4 chunked-XCD cols-fastest-within-chunk (A row-tile L2-reuse).
// nRloc = ceil(nR/8); grid = 8*nRloc*nC for MAP 3/4.
template<int EPI, int OS, int MAP>
__global__ __launch_bounds__(256) void mgemm_k(const unsigned short* __restrict__ Ah,
                                               const unsigned short* __restrict__ Wh,
                                               const float* __restrict__ bias,
                                               const unsigned short* __restrict__ res,
                                               unsigned short* __restrict__ Chi,
                                               float* __restrict__ Cf,
                                               int M, int N, int K, int nR, int nC, int nRloc)
{
    __shared__ unsigned short lds[3 * 8192];   // 3 slots x (A 8KB + B 8KB) = 48 KiB

    int rt, ct;
    {
        int bid = blockIdx.x;
        if (MAP == 0) { rt = bid % nR; ct = bid / nR; }
        else {
            int xcd = bid & 7, u = bid >> 3, rl, c;
            if (MAP == 3) { rl = u % nRloc; c = u / nRloc; }
            else          { c = u % nC;     rl = u / nC;   }
            rt = xcd * nRloc + rl; ct = c;
            if (rt >= nR) return;
        }
    }
    const int row0 = rt << 7, col0 = ct << 7;
    const int tid = threadIdx.x;
    const int w = tid >> 6, lane = tid & 63;
    const int wr = w >> 1, wc = w & 1;
    const int srow = lane >> 2;
    const int schunk = ((lane & 3) ^ ((srow >> 1) & 3)) << 3;   // pre-swizzled source chunk
    const int fr = lane & 15, fq = lane >> 4;
    const int rchunk = (fq ^ ((fr >> 1) & 3)) << 3;             // swizzled read chunk

    f32x4 acc[4][4];
#pragma unroll
    for (int m = 0; m < 4; m++)
#pragma unroll
        for (int n = 0; n < 4; n++) acc[m][n] = (f32x4)0.f;

    const int nk = K >> 5;

    auto stage = [&](int t, int slot) {
        const int k0 = t << 5;
        unsigned short* Ad = lds + slot * 8192;
        unsigned short* Bd = Ad + 4096;
#pragma unroll
        for (int i = 0; i < 2; i++) {
            int r = i * 64 + w * 16 + srow;
            int ga = row0 + r; if (ga > M - 1) ga = M - 1;
            int gb = col0 + r; if (gb > N - 1) gb = N - 1;
            gload16(Ah + (size_t)ga * K + k0 + schunk, Ad + i * 2048 + w * 512);
            gload16(Wh + (size_t)gb * K + k0 + schunk, Bd + i * 2048 + w * 512);
        }
    };

    stage(0, 0);
    stage(1, 1);
    int slot = 0, slot2 = 2;       // slot of tile t; slot of tile t+2
    for (int t = 0; t < nk; ++t) {
        if (t + 1 < nk) asm volatile("s_waitcnt vmcnt(4)" ::: "memory");
        else            asm volatile("s_waitcnt vmcnt(0)" ::: "memory");
        __builtin_amdgcn_s_barrier();              // slot `slot` fully staged everywhere
        if (t + 2 < nk) stage(t + 2, slot2);       // distinct slot: readers retired pre-barrier
        const unsigned short* Ab = lds + slot * 8192;
        const unsigned short* Bb = Ab + 4096;
        half8 a[4], bb[4];
#pragma unroll
        for (int m = 0; m < 4; m++)
            a[m] = *(const half8*)(Ab + (wr * 64 + m * 16 + fr) * 32 + rchunk);
#pragma unroll
        for (int n = 0; n < 4; n++)
            bb[n] = *(const half8*)(Bb + (wc * 64 + n * 16 + fr) * 32 + rchunk);
#pragma unroll
        for (int m = 0; m < 4; m++)
#pragma unroll
            for (int n = 0; n < 4; n++)
                acc[m][n] = __builtin_amdgcn_mfma_f32_16x16x32_f16(a[m], bb[n], acc[m][n], 0, 0, 0);
        slot = (slot == 2) ? 0 : slot + 1;
        slot2 = (slot2 == 2) ? 0 : slot2 + 1;
    }

#pragma unroll
    for (int m = 0; m < 4; m++) {
#pragma unroll
        for (int n = 0; n < 4; n++) {
            int col = col0 + wc * 64 + n * 16 + fr;
#pragma unroll
            for (int r = 0; r < 4; r++) {
                int row = row0 + wr * 64 + m * 16 + fq * 4 + r;
                if (row < M && col < N) {
                    float v = acc[m][n][r] + bias[col];
                    size_t o = (size_t)row * N + col;
                    if (EPI == 2) v += h2f(res[o]);
                    if (EPI == 1) v = 0.5f * v * (1.f + erff(v * 0.70710678118654752f));
                    if (OS == 0) Cf[o] = v;
                    else Chi[o] = f2h(v);
                }
            }
        }
    }
}

// ---------------------------------------------------------------- fused MFMA attention (fp16)
template<int S, int KT, int PVKT, int PSTR>
__global__ __launch_bounds__(256) void attn2_k(const unsigned short* __restrict__ qh,
                                               unsigned short* __restrict__ oh,
                                               const int* __restrict__ cntp)
{
    constexpr int PVK = PVKT * 32;
    constexpr int QT = (S + 15) / 16;
    extern __shared__ unsigned short sh[];
    unsigned short* VT = sh;                 // [64][PSTR]  V^T
    unsigned short* PL = sh + 64 * PSTR;     // 4 waves x [16][PSTR]

    const int h = blockIdx.x, b = blockIdx.y;
    const int tid = threadIdx.x, w = tid >> 6, lane = tid & 63;
    const int nk = cntp ? cntp[b] : S;
    const size_t qbase = (size_t)b * S * 2304 + (size_t)h * 64;
    const int fr = lane & 15, fq = lane >> 4;

    for (int j0 = 0; j0 < S; j0 += 32) {
        int j = j0 + (tid >> 3);
        int d8 = (tid & 7) * 8;
        if (j < S) {
            size_t src = qbase + (size_t)j * 2304 + 1536 + d8;
            us4 v0 = *(const us4*)(qh + src);
            us4 v1 = *(const us4*)(qh + src + 4);
            VT[(d8 + 0) * PSTR + j] = v0.x; VT[(d8 + 1) * PSTR + j] = v0.y;
            VT[(d8 + 2) * PSTR + j] = v0.z; VT[(d8 + 3) * PSTR + j] = v0.w;
            VT[(d8 + 4) * PSTR + j] = v1.x; VT[(d8 + 5) * PSTR + j] = v1.y;
            VT[(d8 + 6) * PSTR + j] = v1.z; VT[(d8 + 7) * PSTR + j] = v1.w;
        }
    }
    for (int idx = tid; idx < 64 * (PVK - S); idx += 256) {
        int d = idx / (PVK - S), j = S + idx % (PVK - S);
        VT[d * PSTR + j] = 0;
    }
    {
        unsigned short* Pw = PL + w * 16 * PSTR;
        for (int idx = lane; idx < 16 * (PVK - 16 * KT); idx += 64) {
            int rr = idx / (PVK - 16 * KT), cc = 16 * KT + idx % (PVK - 16 * KT);
            Pw[rr * PSTR + cc] = 0;
        }
    }
    __syncthreads();

    for (int qt = w; qt < QT; qt += 4) {
        int qr = qt * 16 + fr; int qrc = qr < S ? qr : S - 1;
        const size_t qrow = qbase + (size_t)qrc * 2304;
        half8 qf0[2];
#pragma unroll
        for (int ks = 0; ks < 2; ks++)
            qf0[ks] = *(const half8*)(qh + qrow + ks * 32 + fq * 8);
        f32x4 sc[KT];
#pragma unroll
        for (int kt = 0; kt < KT; kt++) {
            int ky = kt * 16 + fr; int kyc = ky < S ? ky : S - 1;
            const size_t krow = qbase + (size_t)kyc * 2304 + 768;
            f32x4 acc = (f32x4)0.f;
#pragma unroll
            for (int ks = 0; ks < 2; ks++) {
                half8 kh = *(const half8*)(qh + krow + ks * 32 + fq * 8);
                acc = __builtin_amdgcn_mfma_f32_16x16x32_f16(qf0[ks], kh, acc, 0, 0, 0);
            }
            sc[kt] = acc;
        }
        float mx[4] = {-3e38f, -3e38f, -3e38f, -3e38f};
#pragma unroll
        for (int kt = 0; kt < KT; kt++) {
            bool valid = (kt * 16 + fr) < nk;
#pragma unroll
            for (int r = 0; r < 4; r++) {
                float s = sc[kt][r] * 0.125f;
                sc[kt][r] = s;
                if (valid) mx[r] = fmaxf(mx[r], s);
            }
        }
#pragma unroll
        for (int off = 1; off < 16; off <<= 1)
#pragma unroll
            for (int r = 0; r < 4; r++) mx[r] = fmaxf(mx[r], __shfl_xor(mx[r], off));
        float sum[4] = {0.f, 0.f, 0.f, 0.f};
#pragma unroll
        for (int kt = 0; kt < KT; kt++) {
            bool valid = (kt * 16 + fr) < nk;
#pragma unroll
            for (int r = 0; r < 4; r++) {
                float p = valid ? __expf(sc[kt][r] - mx[r]) : 0.f;
                sc[kt][r] = p;
                sum[r] += p;
            }
        }
#pragma unroll
        for (int off = 1; off < 16; off <<= 1)
#pragma unroll
            for (int r = 0; r < 4; r++) sum[r] += __shfl_xor(sum[r], off);
        float inv[4];
#pragma unroll
        for (int r = 0; r < 4; r++) inv[r] = 1.f / sum[r];
        unsigned short* Pw = PL + w * 16 * PSTR;
#pragma unroll
        for (int kt = 0; kt < KT; kt++) {
#pragma unroll
            for (int r = 0; r < 4; r++)
                Pw[(fq * 4 + r) * PSTR + kt * 16 + fr] = f2h(sc[kt][r] * inv[r]);
        }
        f32x4 o[4];
#pragma unroll
        for (int n = 0; n < 4; n++) o[n] = (f32x4)0.f;
#pragma unroll
        for (int ks = 0; ks < PVKT; ks++) {
            half8 pa = *(const half8*)(Pw + fr * PSTR + ks * 32 + fq * 8);
#pragma unroll
            for (int n = 0; n < 4; n++) {
                half8 vb = *(const half8*)(VT + (n * 16 + fr) * PSTR + ks * 32 + fq * 8);
                o[n] = __builtin_amdgcn_mfma_f32_16x16x32_f16(pa, vb, o[n], 0, 0, 0);
            }
        }
#pragma unroll
        for (int n = 0; n < 4; n++) {
#pragma unroll
            for (int r = 0; r < 4; r++) {
                int row = qt * 16 + fq * 4 + r;
                if (row < S) {
                    size_t oidx = ((size_t)b * S + row) * 768 + (size_t)h * 64 + n * 16 + fr;
                    oh[oidx] = f2h(o[n][r]);
                }
            }
        }
    }
}

// ---------------------------------------------------------------- prune machinery (fp16 in)
__global__ __launch_bounds__(256) void normsq_k(const unsigned short* __restrict__ x,
                                                float* __restrict__ norms)
{
    const unsigned short* xr = x + (size_t)blockIdx.x * 768;
    int t = threadIdx.x;
    float v0 = h2f(xr[t]), v1 = h2f(xr[t + 256]), v2 = h2f(xr[t + 512]);
    float ss = v0 * v0 + v1 * v1 + v2 * v2;
#pragma unroll
    for (int o = 32; o; o >>= 1) ss += __shfl_xor(ss, o);
    __shared__ float r1[4];
    if ((t & 63) == 0) r1[t >> 6] = ss;
    __syncthreads();
    if (t == 0) norms[blockIdx.x] = r1[0] + r1[1] + r1[2] + r1[3];
}

__global__ __launch_bounds__(256) void topk_k(const float* __restrict__ norms,
                                              int* __restrict__ idxmap, int* __restrict__ cnt)
{
    int b = blockIdx.x, t = threadIdx.x;
    __shared__ float n[NTOK];
    __shared__ unsigned char kp[NTOK];
    if (t < NTOK) n[t] = norms[b * NTOK + t];
    __syncthreads();
    if (t < NTOK) {
        float me = n[t];
        int rank = 0;
        for (int j = 0; j < NTOK; j++) rank += (n[j] > me) || (n[j] == me && j < t);
        kp[t] = (rank < 98) || (t == 0);
    }
    __syncthreads();
    if (t == 0) {
        int c = 0;
        for (int s = 0; s < NTOK; s++) if (kp[s]) idxmap[b * SL + c++] = s;
        cnt[b] = c;
        for (int j = c; j < SL; j++) idxmap[b * SL + j] = 0;
    }
}

__global__ __launch_bounds__(256) void gather_k(const unsigned short* __restrict__ x,
                                                const int* __restrict__ idxmap,
                                                const int* __restrict__ cnt,
                                                unsigned short* __restrict__ xl)
{
    int j = blockIdx.x, b = blockIdx.y;
    size_t dst = ((size_t)b * SL + j) * 768;
    if (j < cnt[b]) {
        int s = idxmap[b * SL + j];
        size_t src = ((size_t)b * NTOK + s) * 768;
        for (int d = threadIdx.x; d < 768; d += 256) xl[dst + d] = x[src + d];
    } else {
        for (int d = threadIdx.x; d < 768; d += 256) xl[dst + d] = 0;
    }
}

// ---------------------------------------------------------------- launch
extern "C" void kernel_launch(void* const* d_in, const int* in_sizes, int n_in,
                              void* d_out, int out_size, void* d_ws, size_t ws_size,
                              hipStream_t stream)
{
    const float* images  = (const float*)d_in[0];
    const float* patch_w = (const float*)d_in[1];
    const float* patch_b = (const float*)d_in[2];
    const float* cls_tok = (const float*)d_in[3];
    const float* pos_emb = (const float*)d_in[4];
    const float* ln1_g   = (const float*)d_in[5];
    const float* ln1_b   = (const float*)d_in[6];
    const float* qkv_w   = (const float*)d_in[7];
    const float* qkv_b   = (const float*)d_in[8];
    const float* proj_w  = (const float*)d_in[9];
    const float* proj_b  = (const float*)d_in[10];
    const float* ln2_g   = (const float*)d_in[11];
    const float* ln2_b   = (const float*)d_in[12];
    const float* fc1_w   = (const float*)d_in[13];
    const float* fc1_b   = (const float*)d_in[14];
    const float* fc2_w   = (const float*)d_in[15];
    const float* fc2_b   = (const float*)d_in[16];
    const float* norm_g  = (const float*)d_in[17];
    const float* norm_b  = (const float*)d_in[18];
    const float* head_w  = (const float*)d_in[19];
    const float* head_b  = (const float*)d_in[20];
    float* outp = (float*)d_out;

    // -------- workspace layout (bytes), ~186 MB --------
    char* W = (char*)d_ws;
    unsigned short* x16  = (unsigned short*)W;                   // 19,365,888
    unsigned short* hbh  = (unsigned short*)(W + 19365888);      // 19,365,888
    char* R = W + 38731776;                                      // 77,463,552 shared
    unsigned short* ph   = (unsigned short*)R;                   // patches [12544*768]
    unsigned short* emb  = (unsigned short*)(R + 19365888);      // patch-GEMM out
    unsigned short* qkh  = (unsigned short*)R;                   // qkv out
    unsigned short* ffh  = (unsigned short*)R;                   // fc1 out
    unsigned short* xl16 = (unsigned short*)(W + 116195328);     // 9,732,096
    unsigned short* wb4  = (unsigned short*)(W + 125927424);     // 4 layers x 14,155,776
    unsigned short* pwh  = (unsigned short*)(W + 182550528);     // patch_w fp16
    unsigned short* hwb  = (unsigned short*)(W + 183730176);     // head_w fp16
    float* norms         = (float*)(W + 185303040);
    unsigned short* clsb = (unsigned short*)(W + 185353472);
    int* idxmap          = (int*)(W + 185451776);
    int* cnt             = (int*)(W + 185477120);

    const int LDS_EARLY = (64 * 232 + 4 * 16 * 232) * 2;   // 59,392
    const int LDS_LATE  = (64 * 136 + 4 * 16 * 136) * 2;   // 34,816
    (void)hipFuncSetAttribute(reinterpret_cast<const void*>(&attn2_k<197, 13, 7, 232>),
                              hipFuncAttributeMaxDynamicSharedMemorySize, LDS_EARLY);
    (void)hipFuncSetAttribute(reinterpret_cast<const void*>(&attn2_k<99, 7, 4, 136>),
                              hipFuncAttributeMaxDynamicSharedMemorySize, LDS_LATE);

    // chunked grids: grid = 8 * nRloc * nC, nRloc = ceil(nR/8)
    const int nR1 = 99, nRl1 = 13;     // M = 12608
    const int nRp = 98, nRlp = 13;     // patch M = 12544
    const int nR2 = 50, nRl2 = 7;      // M = 6336

    // ---- patch embed ----
    cvt_simple_k<<<576, 256, 0, stream>>>(patch_w, pwh, 147456);
    patch_extract2_k<<<dim3(196, NB), 256, 0, stream>>>(images, ph);
    mgemm_k<0, 1, 3><<<8 * nRlp * 6, 256, 0, stream>>>(ph, pwh, patch_b, nullptr,
        emb, nullptr, 12544, 768, 768, nRp, 6, nRlp);
    assemble_k<<<dim3(NTOK, NB), 256, 0, stream>>>(emb, cls_tok, pos_emb, x16);

    const int M1 = NB * NTOK;   // 12608
    for (int i = 0; i < 4; i++) {
        if (i == 0)
            cvt_layer4_k<<<4 * 6912, 256, 0, stream>>>(qkv_w, proj_w, fc1_w, fc2_w, 0, wb4);
        unsigned short* wbh = wb4 + (size_t)(i & 3) * 7077888;
        ln2_k<<<M1, 256, 0, stream>>>(x16, hbh, ln1_g + (size_t)i * 768, ln1_b + (size_t)i * 768, 768);
        mgemm_k<0, 1, 3><<<8 * nRl1 * 18, 256, 0, stream>>>(hbh, wbh,
            qkv_b + (size_t)i * 2304, nullptr, qkh, nullptr, M1, 2304, 768, nR1, 18, nRl1);
        attn2_k<197, 13, 7, 232><<<dim3(NHEAD, NB), 256, LDS_EARLY, stream>>>(qkh, hbh, nullptr);
        mgemm_k<2, 1, 3><<<8 * nRl1 * 6, 256, 0, stream>>>(hbh, wbh + 1769472,
            proj_b + (size_t)i * 768, x16, x16, nullptr, M1, 768, 768, nR1, 6, nRl1);
        ln2_k<<<M1, 256, 0, stream>>>(x16, hbh, ln2_g + (size_t)i * 768, ln2_b + (size_t)i * 768, 768);
        mgemm_k<1, 1, 3><<<8 * nRl1 * 24, 256, 0, stream>>>(hbh, wbh + 2359296,
            fc1_b + (size_t)i * 3072, nullptr, ffh, nullptr, M1, 3072, 768, nR1, 24, nRl1);
        mgemm_k<2, 1, 4><<<8 * nRl1 * 6, 256, 0, stream>>>(ffh, wbh + 4718592,
            fc2_b + (size_t)i * 768, x16, x16, nullptr, M1, 768, 3072, nR1, 6, nRl1);
    }

    // ---- prune + compact ----
    normsq_k<<<M1, 256, 0, stream>>>(x16, norms);
    topk_k<<<NB, 256, 0, stream>>>(norms, idxmap, cnt);
    gather_k<<<dim3(SL, NB), 256, 0, stream>>>(x16, idxmap, cnt, xl16);

    const int M2 = NB * SL;     // 6336
    for (int i = 4; i < 12; i++) {
        if (i == 4)
            cvt_layer4_k<<<4 * 6912, 256, 0, stream>>>(qkv_w, proj_w, fc1_w, fc2_w, 4, wb4);
        if (i == 8)
            cvt_layer4_k<<<4 * 6912, 256, 0, stream>>>(qkv_w, proj_w, fc1_w, fc2_w, 8, wb4);
        unsigned short* wbh = wb4 + (size_t)(i & 3) * 7077888;
        ln2_k<<<M2, 256, 0, stream>>>(xl16, hbh, ln1_g + (size_t)i * 768, ln1_b + (size_t)i * 768, 768);
        mgemm_k<0, 1, 3><<<8 * nRl2 * 18, 256, 0, stream>>>(hbh, wbh,
            qkv_b + (size_t)i * 2304, nullptr, qkh, nullptr, M2, 2304, 768, nR2, 18, nRl2);
        attn2_k<99, 7, 4, 136><<<dim3(NHEAD, NB), 256, LDS_LATE, stream>>>(qkh, hbh, cnt);
        mgemm_k<2, 1, 3><<<8 * nRl2 * 6, 256, 0, stream>>>(hbh, wbh + 1769472,
            proj_b + (size_t)i * 768, xl16, xl16, nullptr, M2, 768, 768, nR2, 6, nRl2);
        ln2_k<<<M2, 256, 0, stream>>>(xl16, hbh, ln2_g + (size_t)i * 768, ln2_b + (size_t)i * 768, 768);
        mgemm_k<1, 1, 3><<<8 * nRl2 * 24, 256, 0, stream>>>(hbh, wbh + 2359296,
            fc1_b + (size_t)i * 3072, nullptr, ffh, nullptr, M2, 3072, 768, nR2, 24, nRl2);
        mgemm_k<2, 1, 4><<<8 * nRl2 * 6, 256, 0, stream>>>(ffh, wbh + 4718592,
            fc2_b + (size_t)i * 768, xl16, xl16, nullptr, M2, 768, 3072, nR2, 6, nRl2);
    }

    // ---- final LN(CLS) + head ----
    ln2_k<<<NB, 256, 0, stream>>>(xl16, clsb, norm_g, norm_b, (size_t)SL * 768);
    cvt_simple_k<<<750, 256, 0, stream>>>(head_w, hwb, 192000);
    mgemm_k<0, 0, 0><<<8, 256, 0, stream>>>(clsb, hwb,
        head_b, nullptr, nullptr, outp, 64, 1000, 768, 1, 8, 1);
}